// Round 1
// baseline (110.690 us; speedup 1.0000x reference)
//
#include <hip/hip_runtime.h>

// ---- problem constants (fixed by harness) ----
// x[16,64,96,96] f32, dict[100,64,3,3] f32, coeff[256,3,3,3] f32, idx[256,3,3,3] i32
// out[16,256,96,96] f32
#define NB   16
#define CIN  64
#define HH   96
#define WW   96
#define DD   100
#define OO   256

typedef __attribute__((ext_vector_type(8))) short  bf16x8;
typedef __attribute__((ext_vector_type(4))) float  f32x4;

static __device__ __forceinline__ unsigned short f32_to_bf16(float f) {
    unsigned int u = __float_as_uint(f);
    u += 0x7FFFu + ((u >> 16) & 1u);   // round-to-nearest-even
    return (unsigned short)(u >> 16);
}

// ---- prep 1: Wmat[o][d] = scatter-add of coefficients (deterministic: one thread per o) ----
__global__ void make_wmat(const float* __restrict__ coeff, const int* __restrict__ idx,
                          float* __restrict__ wmat) {
    int o = blockIdx.x * 256 + threadIdx.x;
    if (o >= OO) return;
    float* row = wmat + o * DD;
    for (int d = 0; d < DD; ++d) row[d] = 0.f;
    for (int s = 0; s < 27; ++s) {
        int e = o * 27 + s;
        row[idx[e]] += coeff[e];
    }
}

// ---- prep 2: W_eff bf16, layout [o][kpos][c], kpos = kh*3+kw ----
__global__ void make_weff(const float* __restrict__ wmat, const float* __restrict__ dict,
                          unsigned short* __restrict__ weff) {
    int i = blockIdx.x * 256 + threadIdx.x;      // over 256*576
    if (i >= OO * 576) return;
    int o = i / 576, rem = i % 576;
    int kpos = rem / CIN, c = rem % CIN;
    float s = 0.f;
    for (int d = 0; d < DD; ++d)
        s += wmat[o * DD + d] * dict[d * 576 + c * 9 + kpos];
    weff[i] = f32_to_bf16(s);
}

// ---- prep 3: x f32 NCHW -> bf16 NHWC  (x2[b][h][w][c]) ----
__global__ __launch_bounds__(256) void xprep(const float* __restrict__ x,
                                             unsigned short* __restrict__ x2) {
    __shared__ unsigned short lds[CIN * 100];    // [c][w] stride 100 (pad for banks/alignment)
    int blk = blockIdx.x;                        // b*96 + h
    int b = blk / HH, h = blk % HH;
    int tid = threadIdx.x;

    // phase 1: coalesced float4 reads along w, per channel row
    for (int it = 0; it < 6; ++it) {
        int i = tid + it * 256;                  // over 64*24 float4 units
        int c = i / 24, w4 = i % 24;
        const float4* src = reinterpret_cast<const float4*>(
            x + (((size_t)(b * CIN + c) * HH + h) * WW + w4 * 4));
        float4 v = *src;
        ushort4 u;
        u.x = f32_to_bf16(v.x); u.y = f32_to_bf16(v.y);
        u.z = f32_to_bf16(v.z); u.w = f32_to_bf16(v.w);
        *reinterpret_cast<ushort4*>(&lds[c * 100 + w4 * 4]) = u;
    }
    __syncthreads();
    // phase 2: transposed write-out, c-contiguous ushort4
    for (int it = 0; it < 6; ++it) {
        int i = tid + it * 256;                  // over 96*16 ushort4 units of [w][c]
        int w = i / 16, c = (i % 16) * 4;
        ushort4 u;
        u.x = lds[(c + 0) * 100 + w];
        u.y = lds[(c + 1) * 100 + w];
        u.z = lds[(c + 2) * 100 + w];
        u.w = lds[(c + 3) * 100 + w];
        *reinterpret_cast<ushort4*>(x2 + (((size_t)(b * HH + h) * WW + w) * CIN + c)) = u;
    }
}

// ---- main conv: block = (b,h) output row; 8 waves; M=O=256, N=w=96, K=9*64 ----
__global__ __launch_bounds__(512, 4) void conv_kernel(
    const unsigned short* __restrict__ x2,     // [16][96][96][64] bf16 (NHWC)
    const unsigned short* __restrict__ weff,   // [256][9][64] bf16
    float* __restrict__ out)                   // [16][256][96][96] f32
{
    __shared__ unsigned short xs[3 * 98 * 64]; // 3 input rows, wp in [0,98), swizzled. 37632 B
    __shared__ unsigned short wt[OO * CIN];    // one kpos W slab, swizzled. 32768 B

    const int blk = blockIdx.x;                // b*96 + h
    const int b = blk / HH, h = blk % HH;
    const int tid = threadIdx.x;
    const int lane = tid & 63, wid = tid >> 6;

    char* xsb = reinterpret_cast<char*>(xs);
    char* wtb = reinterpret_cast<char*>(wt);

    // ---- stage 3 x rows (h-1..h+1) into LDS, once ----
    for (int it = 0; it < 5; ++it) {
        int chunk = tid + it * 512;            // 3*96*8 = 2304 chunks of 16B
        if (chunk < 2304) {
            int r = chunk / 768, rem = chunk % 768;
            int w = rem >> 3, c0 = (rem & 7) * 8;
            int hp = h - 1 + r;
            int wp = w + 1;
            int lb = r * 12544 + ((wp * 64 + c0) * 2 ^ ((wp & 7) << 4));
            bf16x8 v = {0,0,0,0,0,0,0,0};
            if (hp >= 0 && hp < HH)
                v = *reinterpret_cast<const bf16x8*>(
                    x2 + (((size_t)(b * HH + hp) * WW + w) * CIN + c0));
            *reinterpret_cast<bf16x8*>(xsb + lb) = v;
        }
    }
    // zero pad columns wp=0 and wp=97
    if (tid < 48) {
        int r = tid / 16, side = (tid & 15) >> 3, ci = tid & 7;
        int wp = side ? 97 : 0;
        int lb = r * 12544 + ((wp * 64 + ci * 8) * 2 ^ ((wp & 7) << 4));
        bf16x8 z = {0,0,0,0,0,0,0,0};
        *reinterpret_cast<bf16x8*>(xsb + lb) = z;
    }

    // ---- issue W loads for kpos 0 ----
    bf16x8 wreg[4];
#pragma unroll
    for (int i = 0; i < 4; ++i) {
        int chunk = tid + i * 512;             // 2048 chunks of 16B (32 KB)
        int o = chunk >> 3, c0 = (chunk & 7) * 8;
        wreg[i] = *reinterpret_cast<const bf16x8*>(weff + (o * 9 + 0) * CIN + c0);
    }

    f32x4 acc[2][6];
#pragma unroll
    for (int m = 0; m < 2; ++m)
#pragma unroll
        for (int n = 0; n < 6; ++n)
            acc[m][n] = (f32x4){0.f, 0.f, 0.f, 0.f};

    __syncthreads();                           // xs staged

    const int mo = wid * 32;                   // this wave's O-slice base

    for (int kpos = 0; kpos < 9; ++kpos) {
        // write staged W slab into LDS (swizzled by o)
#pragma unroll
        for (int i = 0; i < 4; ++i) {
            int chunk = tid + i * 512;
            int o = chunk >> 3, c0 = (chunk & 7) * 8;
            int lb = (o * CIN + c0) * 2 ^ ((o & 7) << 4);
            *reinterpret_cast<bf16x8*>(wtb + lb) = wreg[i];
        }
        __syncthreads();                       // wt ready

        // prefetch next slab under this kpos's MFMAs
        if (kpos < 8) {
#pragma unroll
            for (int i = 0; i < 4; ++i) {
                int chunk = tid + i * 512;
                int o = chunk >> 3, c0 = (chunk & 7) * 8;
                wreg[i] = *reinterpret_cast<const bf16x8*>(weff + (o * 9 + kpos + 1) * CIN + c0);
            }
        }

        const int r = kpos / 3, dw = kpos % 3;
        const int xbase = r * 12544;
#pragma unroll
        for (int ks = 0; ks < 2; ++ks) {
            const int c = ks * 32 + (lane >> 4) * 8;
            bf16x8 afr[2];
#pragma unroll
            for (int m = 0; m < 2; ++m) {
                int o = mo + m * 16 + (lane & 15);
                int lb = (o * CIN + c) * 2 ^ ((o & 7) << 4);
                afr[m] = *reinterpret_cast<const bf16x8*>(wtb + lb);
            }
#pragma unroll
            for (int n = 0; n < 6; ++n) {
                int wcol = n * 16 + (lane & 15);
                int wp = wcol + dw;            // dw in {0,1,2} == kw; pad already at +1
                int lb = xbase + ((wp * 64 + c) * 2 ^ ((wp & 7) << 4));
                bf16x8 bfr = *reinterpret_cast<const bf16x8*>(xsb + lb);
#pragma unroll
                for (int m = 0; m < 2; ++m)
                    acc[m][n] = __builtin_amdgcn_mfma_f32_16x16x32_bf16(
                        afr[m], bfr, acc[m][n], 0, 0, 0);
            }
        }
        if (kpos < 8) __syncthreads();         // all reads of wt done before overwrite
    }

    // ---- epilogue: D row = o = (lane>>4)*4+j, col = w = lane&15 ----
#pragma unroll
    for (int m = 0; m < 2; ++m) {
#pragma unroll
        for (int n = 0; n < 6; ++n) {
            int wcol = n * 16 + (lane & 15);
#pragma unroll
            for (int j = 0; j < 4; ++j) {
                int o = mo + m * 16 + (lane >> 4) * 4 + j;
                out[(((size_t)(b * OO + o) * HH) + h) * WW + wcol] = acc[m][n][j];
            }
        }
    }
}

extern "C" void kernel_launch(void* const* d_in, const int* in_sizes, int n_in,
                              void* d_out, int out_size, void* d_ws, size_t ws_size,
                              hipStream_t stream) {
    const float* x     = (const float*)d_in[0];
    const float* dict  = (const float*)d_in[1];
    const float* coeff = (const float*)d_in[2];
    const int*   idx   = (const int*)d_in[3];
    float* out = (float*)d_out;

    char* ws = (char*)d_ws;
    float*          wmat = (float*)ws;                         // 256*100*4 = 102400 B
    unsigned short* weff = (unsigned short*)(ws + 131072);     // 256*576*2 = 294912 B
    unsigned short* x2   = (unsigned short*)(ws + 1048576);    // 16*96*96*64*2 = 18874368 B

    make_wmat<<<1, 256, 0, stream>>>(coeff, idx, wmat);
    make_weff<<<(OO * 576 + 255) / 256, 256, 0, stream>>>(wmat, dict, weff);
    xprep<<<NB * HH, 256, 0, stream>>>(x, x2);
    conv_kernel<<<NB * HH, 512, 0, stream>>>(x2, weff, out);
}

// Round 2
// 82.194 us; speedup vs baseline: 1.3467x; 1.3467x over previous
//
#include <hip/hip_runtime.h>

// x[16,64,96,96] f32, dict[100,64,3,3] f32, coeff[256,3,3,3] f32, idx[256,3,3,3] i32
// out[16,256,96,96] f32
#define NB   16
#define CIN  64
#define HH   96
#define WW   96
#define DD   100
#define OO   256
#define NWG  (NB * HH)   // 1536

typedef __attribute__((ext_vector_type(8))) short  bf16x8;
typedef __attribute__((ext_vector_type(4))) float  f32x4;

static __device__ __forceinline__ unsigned short f32_to_bf16(float f) {
    unsigned int u = __float_as_uint(f);
    u += 0x7FFFu + ((u >> 16) & 1u);   // RNE
    return (unsigned short)(u >> 16);
}

// ---- fused prep:
//  blocks [0, 1536): x f32 NCHW -> bf16 NHWC row transpose (x2[b][h][w][c])
//  blocks [1536, 1792): per-o W_eff = (scatter(coeff,idx) @ dict), written in
//    MFMA B-fragment lane order: frag(kpos, otile, ks) is 1KB, lane*16B inside.
__global__ __launch_bounds__(256) void prep_kernel(
    const float* __restrict__ x, const float* __restrict__ dict,
    const float* __restrict__ coeff, const int* __restrict__ idx,
    unsigned short* __restrict__ x2, unsigned short* __restrict__ weff2)
{
    __shared__ unsigned short lds[CIN * 100];
    __shared__ float wrow[DD];
    const int blk = blockIdx.x, tid = threadIdx.x;

    if (blk < NWG) {
        const int b = blk / HH, h = blk % HH;
        // coalesced float4 reads along w, per channel row
        for (int it = 0; it < 6; ++it) {
            int i = tid + it * 256;                  // 64*24 float4 units
            int c = i / 24, w4 = i % 24;
            float4 v = *reinterpret_cast<const float4*>(
                x + (((size_t)(b * CIN + c) * HH + h) * WW + w4 * 4));
            ushort4 u;
            u.x = f32_to_bf16(v.x); u.y = f32_to_bf16(v.y);
            u.z = f32_to_bf16(v.z); u.w = f32_to_bf16(v.w);
            *reinterpret_cast<ushort4*>(&lds[c * 100 + w4 * 4]) = u;
        }
        __syncthreads();
        // transposed write-out, c-contiguous
        for (int it = 0; it < 6; ++it) {
            int i = tid + it * 256;                  // 96*16 ushort4 units
            int w = i / 16, c = (i % 16) * 4;
            ushort4 u;
            u.x = lds[(c + 0) * 100 + w];
            u.y = lds[(c + 1) * 100 + w];
            u.z = lds[(c + 2) * 100 + w];
            u.w = lds[(c + 3) * 100 + w];
            *reinterpret_cast<ushort4*>(x2 + (((size_t)(b * HH + h) * WW + w) * CIN + c)) = u;
        }
    } else {
        const int o = blk - NWG;
        if (tid < DD) wrow[tid] = 0.f;
        __syncthreads();
        if (tid == 0) {                              // deterministic serial scatter
            for (int s = 0; s < 27; ++s) wrow[idx[o * 27 + s]] += coeff[o * 27 + s];
        }
        __syncthreads();
        for (int j = tid; j < 576; j += 256) {       // j = kpos*64 + c
            int kpos = j >> 6, c = j & 63;
            float s = 0.f;
            for (int d = 0; d < DD; ++d)
                s += wrow[d] * dict[d * 576 + c * 9 + kpos];
            int otile = o >> 4, ks = c >> 5;
            int lane8 = (o & 15) | (((c >> 3) & 3) << 4);
            weff2[((size_t)((kpos * 16 + otile) * 2 + ks)) * 512 + lane8 * 8 + (c & 7)]
                = f32_to_bf16(s);
        }
    }
}

// ---- conv: block = (b,h) output row; 8 waves in 2(w-half) x 4(o-quarter) grid.
// M = w (96), N = o (256), K = 9 kpos x 64 c. No barriers in the k-loop.
__global__ __launch_bounds__(512, 4) void conv_kernel(
    const unsigned short* __restrict__ x2,     // [16][96][96][64] bf16 NHWC
    const unsigned short* __restrict__ weff2,  // fragment-ordered, 288KB (L2-resident)
    float* __restrict__ out)                   // [16][256][96][96] f32
{
    __shared__ unsigned short xs[3 * 98 * 64]; // 3 rows, wp in [0,98), XOR-swizzled

    const int wg  = blockIdx.x;
    const int swz = (wg & 7) * (NWG / 8) + (wg >> 3);   // XCD-bijective (1536%8==0)
    const int b = swz / HH, h = swz % HH;
    const int tid = threadIdx.x;
    const int lane = tid & 63, wid = tid >> 6;
    const int wm = wid >> 2, wn = wid & 3;     // wm: w-half, wn: o-quarter

    char* xsb = reinterpret_cast<char*>(xs);

    // ---- stage 3 x rows (h-1..h+1) into LDS, once ----
    for (int it = 0; it < 5; ++it) {
        int chunk = tid + it * 512;            // 3*96*8 = 2304 chunks of 16B
        if (chunk < 2304) {
            int r = chunk / 768, rem = chunk % 768;
            int w = rem >> 3, c0 = (rem & 7) * 8;
            int hp = h - 1 + r;
            int wp = w + 1;
            int lb = r * 12544 + (((wp * 64 + c0) * 2) ^ ((wp & 7) << 4));
            bf16x8 v = {0,0,0,0,0,0,0,0};
            if (hp >= 0 && hp < HH)
                v = *reinterpret_cast<const bf16x8*>(
                    x2 + (((size_t)(b * HH + hp) * WW + w) * CIN + c0));
            *reinterpret_cast<bf16x8*>(xsb + lb) = v;
        }
    }
    if (tid < 48) {                            // zero pad wp=0 and wp=97
        int r = tid / 16, side = (tid & 15) >> 3, ci = tid & 7;
        int wp = side ? 97 : 0;
        int lb = r * 12544 + (((wp * 64 + ci * 8) * 2) ^ ((wp & 7) << 4));
        bf16x8 z = {0,0,0,0,0,0,0,0};
        *reinterpret_cast<bf16x8*>(xsb + lb) = z;
    }

    f32x4 acc[3][4];
#pragma unroll
    for (int m = 0; m < 3; ++m)
#pragma unroll
        for (int n = 0; n < 4; ++n)
            acc[m][n] = (f32x4){0.f, 0.f, 0.f, 0.f};

    __syncthreads();                           // xs staged (only barrier)

    for (int kpos = 0; kpos < 9; ++kpos) {
        // B-fragments for this wave's 4 o-tiles, both k-halves: coalesced 1KB loads from L2
        bf16x8 bfr[2][4];
#pragma unroll
        for (int ks = 0; ks < 2; ++ks)
#pragma unroll
            for (int n = 0; n < 4; ++n) {
                int frag = (kpos * 16 + (wn * 4 + n)) * 2 + ks;
                bfr[ks][n] = *reinterpret_cast<const bf16x8*>(
                    weff2 + (size_t)frag * 512 + lane * 8);
            }

        const int r = kpos / 3, dw = kpos % 3;
        const int xbase = r * 12544;
#pragma unroll
        for (int ks = 0; ks < 2; ++ks) {
            const int c = ks * 32 + (lane >> 4) * 8;
#pragma unroll
            for (int m = 0; m < 3; ++m) {
                int wp = wm * 48 + m * 16 + (lane & 15) + dw;
                int lb = xbase + (((wp * 64 + c) * 2) ^ ((wp & 7) << 4));
                bf16x8 a = *reinterpret_cast<const bf16x8*>(xsb + lb);
#pragma unroll
                for (int n = 0; n < 4; ++n)
                    acc[m][n] = __builtin_amdgcn_mfma_f32_16x16x32_bf16(
                        a, bfr[ks][n], acc[m][n], 0, 0, 0);
            }
        }
    }

    // ---- epilogue: lane holds 4 consecutive w (row=(lane>>4)*4+j), o = col=lane&15
#pragma unroll
    for (int m = 0; m < 3; ++m) {
#pragma unroll
        for (int n = 0; n < 4; ++n) {
            int o = wn * 64 + n * 16 + (lane & 15);
            int w = wm * 48 + m * 16 + (lane >> 4) * 4;
            *reinterpret_cast<float4*>(
                out + (((size_t)(b * OO + o) * HH + h) * WW + w))
                = *reinterpret_cast<float4*>(&acc[m][n]);
        }
    }
}

extern "C" void kernel_launch(void* const* d_in, const int* in_sizes, int n_in,
                              void* d_out, int out_size, void* d_ws, size_t ws_size,
                              hipStream_t stream) {
    const float* x     = (const float*)d_in[0];
    const float* dict  = (const float*)d_in[1];
    const float* coeff = (const float*)d_in[2];
    const int*   idx   = (const int*)d_in[3];
    float* out = (float*)d_out;

    char* ws = (char*)d_ws;
    unsigned short* weff2 = (unsigned short*)ws;               // 294912 B
    unsigned short* x2    = (unsigned short*)(ws + 1048576);   // 18874368 B

    prep_kernel<<<NWG + OO, 256, 0, stream>>>(x, dict, coeff, idx, x2, weff2);
    conv_kernel<<<NWG, 512, 0, stream>>>(x2, weff2, out);
}